// Round 4
// baseline (173.272 us; speedup 1.0000x reference)
//
#include <hip/hip_runtime.h>
#include <hip/hip_bf16.h>
#include <cstdint>

typedef unsigned short u16;
typedef __bf16 bf16x8 __attribute__((ext_vector_type(8)));
typedef float f32x4 __attribute__((ext_vector_type(4)));
typedef float f32x8 __attribute__((ext_vector_type(8)));
typedef unsigned short u16x4 __attribute__((ext_vector_type(4)));
typedef unsigned short u16x8 __attribute__((ext_vector_type(8)));

#define BB 8
#define SS 512
#define NN 2048
#define HH 512
#define MM (BB*NN)   // 16384

__device__ inline u16 f2b(float f) {
  __hip_bfloat16 h = __float2bfloat16(f);
  return *reinterpret_cast<u16*>(&h);
}
__device__ inline float b2f(u16 u) {
  unsigned x = ((unsigned)u) << 16;
  return __uint_as_float(x);
}
__device__ inline f32x8 b2f8(u16x8 v) {
  f32x8 r;
  #pragma unroll
  for (int k = 0; k < 8; ++k) r[k] = b2f(v[k]);
  return r;
}

// ---------- transpose x (B,S,N) -> XR bf16 (B*N, S), plus per-s-block column partial sums ----------
__global__ void k_txr(const float* __restrict__ x, u16* __restrict__ xr, float* __restrict__ fvp) {
  __shared__ float t[32][33];
  __shared__ float ps[8][32];
  const int b = blockIdx.z, n0 = blockIdx.x * 32, s0 = blockIdx.y * 32;
  const int tx = threadIdx.x, ty = threadIdx.y;
  float acc = 0.f;
  for (int i = ty; i < 32; i += 8) {
    float w = x[(size_t)b*SS*NN + (size_t)(s0+i)*NN + (n0+tx)];
    t[i][tx] = w; acc += w;
  }
  ps[ty][tx] = acc;
  __syncthreads();
  if (ty == 0) {
    float s = 0.f;
    #pragma unroll
    for (int j = 0; j < 8; ++j) s += ps[j][tx];
    fvp[((size_t)(b*16 + blockIdx.y))*NN + n0 + tx] = s;
  }
  for (int i = ty; i < 32; i += 8)
    xr[((size_t)b*NN + (n0+i))*SS + (s0+tx)] = f2b(t[tx][i]);
}

// ---------- per-batch top-9 desc/asc selection, class counts, row flags; zero xs/g1s ----------
__global__ __launch_bounds__(256) void k_topk(const float* __restrict__ fvp, int* __restrict__ meta,
                       int* __restrict__ rowfl, float* __restrict__ xs, float* __restrict__ g1s) {
  const int b = blockIdx.x, tid = threadIdx.x;
  const int wv = tid >> 6, ln = tid & 63;
  __shared__ float v[NN];
  __shared__ unsigned long long wk[2][4];
  __shared__ unsigned long long winner[2];
  __shared__ int sel[18];
  __shared__ int scnt[12];
  __shared__ int ccnt[3][4];

  {
    float4 z = {0.f, 0.f, 0.f, 0.f};
    float4* z1 = (float4*)(xs + (size_t)b*12*HH);
    float4* z2 = (float4*)(g1s + (size_t)b*12*HH);
    for (int i = tid; i < 12*HH/4; i += 256) { z1[i] = z; z2[i] = z; }
  }

  float lv[8];
  {
    f32x4 a0 = {0,0,0,0}, a1 = {0,0,0,0};
    for (int sb_ = 0; sb_ < 16; ++sb_) {
      const f32x4* p = (const f32x4*)(fvp + ((size_t)(b*16 + sb_))*NN + tid*8);
      a0 += p[0]; a1 += p[1];
    }
    lv[0]=a0[0]; lv[1]=a0[1]; lv[2]=a0[2]; lv[3]=a0[3];
    lv[4]=a1[0]; lv[5]=a1[1]; lv[6]=a1[2]; lv[7]=a1[3];
  }
  #pragma unroll
  for (int j = 0; j < 8; ++j) v[tid*8+j] = lv[j];

  unsigned long long kD[8], kA[8];
  #pragma unroll
  for (int j = 0; j < 8; ++j) {
    unsigned u = __float_as_uint(lv[j]);
    u = (u & 0x80000000u) ? ~u : (u | 0x80000000u);
    unsigned idx = (unsigned)(tid*8 + j);
    kD[j] = ((unsigned long long)u << 32) | (0xFFFFFFFFu - idx);
    kA[j] = ((unsigned long long)(~u) << 32) | (0xFFFFFFFFu - idx);
  }
  unsigned mskD = 0, mskA = 0;
  for (int r = 0; r < 9; ++r) {
    unsigned long long bD = 0ull, bA = 0ull;
    #pragma unroll
    for (int j = 0; j < 8; ++j) {
      if (!((mskD >> j) & 1) && kD[j] > bD) bD = kD[j];
      if (!((mskA >> j) & 1) && kA[j] > bA) bA = kA[j];
    }
    #pragma unroll
    for (int o = 32; o > 0; o >>= 1) {
      unsigned long long oD = __shfl_xor(bD, o, 64);
      unsigned long long oA = __shfl_xor(bA, o, 64);
      if (oD > bD) bD = oD;
      if (oA > bA) bA = oA;
    }
    if (ln == 0) { wk[0][wv] = bD; wk[1][wv] = bA; }
    __syncthreads();
    if (tid == 0) {
      unsigned long long mD = wk[0][0], mA = wk[1][0];
      #pragma unroll
      for (int q = 1; q < 4; ++q) {
        if (wk[0][q] > mD) mD = wk[0][q];
        if (wk[1][q] > mA) mA = wk[1][q];
      }
      winner[0] = mD; winner[1] = mA;
      sel[r]   = (int)(0xFFFFFFFFu - (unsigned)mD);
      sel[9+r] = (int)(0xFFFFFFFFu - (unsigned)mA);
    }
    __syncthreads();
    unsigned iD = 0xFFFFFFFFu - (unsigned)winner[0];
    unsigned iA = 0xFFFFFFFFu - (unsigned)winner[1];
    if ((int)(iD >> 3) == tid) mskD |= 1u << (iD & 7);
    if ((int)(iA >> 3) == tid) mskA |= 1u << (iA & 7);
  }

  int cp = 0, cn = 0, cz = 0;
  #pragma unroll
  for (int j = 0; j < 8; ++j) { cp += (lv[j] > 0.f); cn += (lv[j] < 0.f); cz += (lv[j] == 0.f); }
  #pragma unroll
  for (int o = 32; o > 0; o >>= 1) { cp += __shfl_xor(cp, o, 64); cn += __shfl_xor(cn, o, 64); cz += __shfl_xor(cz, o, 64); }
  if (ln == 0) { ccnt[0][wv] = cp; ccnt[1][wv] = cn; ccnt[2][wv] = cz; }
  __syncthreads();
  if (tid == 0) {
    int CP = 0, CN = 0, CZ = 0;
    #pragma unroll
    for (int q = 0; q < 4; ++q) { CP += ccnt[0][q]; CN += ccnt[1][q]; CZ += ccnt[2][q]; }
    scnt[0] = CP; scnt[1] = CN; scnt[2] = CZ;
    for (int t = 3; t < 12; ++t) scnt[t] = 0;
    for (int r = 1; r < 9; ++r) {
      float wD = v[sel[r]];   scnt[3] += (wD > 0.f); scnt[4] += (wD < 0.f); scnt[5] += (wD == 0.f);
      float wA = v[sel[9+r]]; scnt[6] += (wA > 0.f); scnt[7] += (wA < 0.f); scnt[8] += (wA == 0.f);
      float wZ = v[r];        scnt[9] += (wZ > 0.f); scnt[10] += (wZ < 0.f); scnt[11] += (wZ == 0.f);
    }
  }
  __syncthreads();
  #pragma unroll
  for (int j = 0; j < 8; ++j) {
    const int i = tid*8 + j;
    float w = lv[j];
    int cls = (w > 0.f) ? 0 : ((w < 0.f) ? 1 : 2);
    int mD = 0, mA = 0;
    #pragma unroll
    for (int r = 1; r < 9; ++r) { mD |= (sel[r] == i); mA |= (sel[9+r] == i); }
    int mZ8 = (i >= 1 && i <= 8);
    rowfl[b*NN + i] = cls | (mD << 2) | (mA << 3) | (mZ8 << 4);
  }
  if (tid < 18) meta[b*32 + tid] = sel[tid];
  if (tid >= 18 && tid < 30) meta[b*32 + tid] = scnt[tid - 18];
}

// ---------- weights: bf16 cast (row-major) + f32 transpose ----------
__global__ void k_wprep(const float* __restrict__ W1, const float* __restrict__ W2,
                        u16* __restrict__ w1b, u16* __restrict__ w2b,
                        float* __restrict__ w1t, float* __restrict__ w2t) {
  __shared__ float t[32][33];
  const float* W = blockIdx.z ? W2 : W1;
  u16* wb = blockIdx.z ? w2b : w1b;
  float* wt = blockIdx.z ? w2t : w1t;
  const int r0 = blockIdx.y * 32, c0 = blockIdx.x * 32;
  const int tx = threadIdx.x, ty = threadIdx.y;
  for (int i = ty; i < 32; i += 8) {
    float vv = W[(size_t)(r0+i)*512 + c0 + tx];
    t[i][tx] = vv;
    wb[(size_t)(r0+i)*512 + c0 + tx] = f2b(vv);
  }
  __syncthreads();
  for (int i = ty; i < 32; i += 8)
    wt[(size_t)(c0+i)*512 + r0 + tx] = t[tx][i];   // wt[k][d] = W[d][k]
}

// ---------- class sums (atomic) + set sums of a bf16 matrix (XR or g1) -> dst[b][12][512] f32 ----------
__global__ __launch_bounds__(256) void k_rowsums(const u16* __restrict__ src, const int* __restrict__ meta,
                      const int* __restrict__ rowfl, float* __restrict__ dst) {
  const int b = blockIdx.x / 33, c = blockIdx.x % 33;
  float* sb = dst + (size_t)b*12*HH;
  const int tid = threadIdx.x;
  const u16* hb = src + (size_t)b*NN*HH;
  if (c == 32) {
    const int* mb = meta + b*32;
    #pragma unroll
    for (int half = 0; half < 2; ++half) {
      const int d = tid + half*256;
      float sdp=0,sdn=0,sdz=0, sap=0,san=0,saz=0, szp=0,szn=0,szz=0;
      for (int r = 1; r < 9; ++r) {
        int iD = mb[r];   int cD = rowfl[b*NN+iD] & 3; float vD = b2f(hb[(size_t)iD*HH + d]);
        sdp += (cD==0)?vD:0.f; sdn += (cD==1)?vD:0.f; sdz += (cD==2)?vD:0.f;
        int iA = mb[9+r]; int cA = rowfl[b*NN+iA] & 3; float vA = b2f(hb[(size_t)iA*HH + d]);
        sap += (cA==0)?vA:0.f; san += (cA==1)?vA:0.f; saz += (cA==2)?vA:0.f;
        int iZ = r;       int cZ = rowfl[b*NN+iZ] & 3; float vZ = b2f(hb[(size_t)iZ*HH + d]);
        szp += (cZ==0)?vZ:0.f; szn += (cZ==1)?vZ:0.f; szz += (cZ==2)?vZ:0.f;
      }
      sb[3*HH+d]=sdp; sb[4*HH+d]=sdn; sb[5*HH+d]=sdz;
      sb[6*HH+d]=sap; sb[7*HH+d]=san; sb[8*HH+d]=saz;
      sb[9*HH+d]=szp; sb[10*HH+d]=szn; sb[11*HH+d]=szz;
    }
    return;
  }
  const int n0 = c * 64;
  const int fc = tid & 63, rg = tid >> 6;
  f32x8 sp = {0,0,0,0,0,0,0,0}, sn = sp, sz = sp;
  for (int it = 0; it < 16; ++it) {
    const int n = n0 + rg + it*4;
    const int cls = rowfl[b*NN + n] & 3;
    u16x8 hv = *(const u16x8*)(hb + (size_t)n*HH + fc*8);
    f32x8 hf = b2f8(hv);
    if (cls == 0) sp += hf; else if (cls == 1) sn += hf; else sz += hf;
  }
  __shared__ f32x8 red[3][4][64];
  red[0][rg][fc] = sp; red[1][rg][fc] = sn; red[2][rg][fc] = sz;
  __syncthreads();
  if (rg == 0) {
    sp = red[0][0][fc] + red[0][1][fc] + red[0][2][fc] + red[0][3][fc];
    sn = red[1][0][fc] + red[1][1][fc] + red[1][2][fc] + red[1][3][fc];
    sz = red[2][0][fc] + red[2][1][fc] + red[2][2][fc] + red[2][3][fc];
    #pragma unroll
    for (int j = 0; j < 8; ++j) {
      atomicAdd(&sb[0*HH + fc*8 + j], sp[j]);
      atomicAdd(&sb[1*HH + fc*8 + j], sn[j]);
      atomicAdd(&sb[2*HH + fc*8 + j], sz[j]);
    }
  }
}

// ---------- mini-GEMM: 12 row-sum vectors @ W^T + cnt*bias, folded into per-combo V table + rdeg ----------
__global__ __launch_bounds__(512) void k_sgemm(const float* __restrict__ xsb, const float* __restrict__ wt,
                       const float* __restrict__ bias, const int* __restrict__ meta,
                       float* __restrict__ V, float* __restrict__ rdt) {
  const int b = blockIdx.y, d0 = blockIdx.x * 128;
  const int tid = threadIdx.x;
  const int dl = tid & 127, vg = tid >> 7;
  __shared__ float xsl[12][512];
  __shared__ float slv[12][128];
  __shared__ int cntl[12];
  for (int i = tid; i < 12*512; i += 512) xsl[i >> 9][i & 511] = xsb[(size_t)b*12*HH + i];
  if (tid < 12) cntl[tid] = meta[b*32 + 18 + tid];
  __syncthreads();
  const int d = d0 + dl;
  const int v0 = vg * 3;
  float a0 = 0.f, a1 = 0.f, a2 = 0.f;
  for (int k = 0; k < 512; ++k) {
    float wv = wt[(size_t)k*512 + d];
    a0 += xsl[v0][k] * wv; a1 += xsl[v0+1][k] * wv; a2 += xsl[v0+2][k] * wv;
  }
  float bv = bias[d];
  slv[v0][dl]   = a0 + (float)cntl[v0]   * bv;
  slv[v0+1][dl] = a1 + (float)cntl[v0+1] * bv;
  slv[v0+2][dl] = a2 + (float)cntl[v0+2] * bv;
  __syncthreads();
  // combo phase: each thread handles 8 fl values for its d
  const int fl0 = vg * 8;
  for (int fl = fl0; fl < fl0 + 8; ++fl) {
    int cls = fl & 3; if (cls == 3) cls = 2;
    int mD = (fl >> 2) & 1, mA = (fl >> 3) & 1, mZ = (fl >> 4) & 1;
    float c3 = mD*slv[0][dl] + mA*slv[1][dl] + mZ*slv[2][dl];
    float c3c = (float)(mD*cntl[0] + mA*cntl[1] + mZ*cntl[2]);
    int rb = 3 + cls*3;
    float c2s = slv[rb][dl] + slv[rb+1][dl] + slv[rb+2][dl]
              - mD*slv[rb][dl] - mA*slv[rb+1][dl] - mZ*slv[rb+2][dl];
    float c2c = (float)(cntl[rb] + cntl[rb+1] + cntl[rb+2]
              - mD*cntl[rb] - mA*cntl[rb+1] - mZ*cntl[rb+2]);
    bool cself = (cls == 0 && mD) || (cls == 1 && mA) || (cls == 2 && mZ);
    float deg = c3c + c2c + (cself ? 0.f : 1.f);
    if (deg < 1.f) deg = 1.f;
    V[((size_t)(b*32 + fl))*512 + d] = (c3 + c2s) / deg;
  }
  if (blockIdx.x == 0 && tid < 32) {
    int fl = tid;
    int cls = fl & 3; if (cls == 3) cls = 2;
    int mD = (fl >> 2) & 1, mA = (fl >> 3) & 1, mZ = (fl >> 4) & 1;
    float c3c = (float)(mD*cntl[0] + mA*cntl[1] + mZ*cntl[2]);
    int rb = 3 + cls*3;
    float c2c = (float)(cntl[rb] + cntl[rb+1] + cntl[rb+2]
              - mD*cntl[rb] - mA*cntl[rb+1] - mZ*cntl[rb+2]);
    bool cself = (cls == 0 && mD) || (cls == 1 && mA) || (cls == 2 && mZ);
    float deg = c3c + c2c + (cself ? 0.f : 1.f);
    if (deg < 1.f) deg = 1.f;
    rdt[b*32 + fl] = 1.f / deg;
  }
}

#define GLOAD16(g, l) __builtin_amdgcn_global_load_lds( \
    (const __attribute__((address_space(1))) void*)(g), \
    (__attribute__((address_space(3))) void*)(l), 16, 0, 0)

// ---------- GEMM1 fused: g1 = relu(V[fl] + (A@W1^T + b1)*rdeg), bf16 out ----------
__global__ __launch_bounds__(256) void k_gemm1f(const u16* __restrict__ A, const u16* __restrict__ Bw,
                       const float* __restrict__ bias, const float* __restrict__ V,
                       const float* __restrict__ rdt, const int* __restrict__ rowfl,
                       u16* __restrict__ G) {
  __shared__ u16 As[128*32];
  __shared__ u16 Bs[128*32];
  const int tid = threadIdx.x;
  const int w = tid >> 6, l = tid & 63;
  const int wm = w >> 1, wn = w & 1;
  const int m0 = blockIdx.x * 128, n0 = blockIdx.y * 128;
  const int b = m0 >> 11;
  f32x4 acc[4][4];
  #pragma unroll
  for (int i = 0; i < 4; ++i)
    #pragma unroll
    for (int j = 0; j < 4; ++j) acc[i][j] = (f32x4){0.f, 0.f, 0.f, 0.f};
  const int srow = l >> 2, skk = (l & 3) * 8;
  for (int kt = 0; kt < 512; kt += 32) {
    #pragma unroll
    for (int p = 0; p < 2; ++p) {
      const int q = w*2 + p;
      GLOAD16(A  + (size_t)(m0 + q*16 + srow)*512 + kt + skk, As + q*512);
      GLOAD16(Bw + (size_t)(n0 + q*16 + srow)*512 + kt + skk, Bs + q*512);
    }
    __syncthreads();
    bf16x8 af[4], bfr[4];
    const int lr = l & 15, lk = (l >> 4) * 8;
    #pragma unroll
    for (int i = 0; i < 4; ++i) af[i] = *(const bf16x8*)(As + (wm*64 + i*16 + lr)*32 + lk);
    #pragma unroll
    for (int j = 0; j < 4; ++j) bfr[j] = *(const bf16x8*)(Bs + (wn*64 + j*16 + lr)*32 + lk);
    #pragma unroll
    for (int i = 0; i < 4; ++i)
      #pragma unroll
      for (int j = 0; j < 4; ++j)
        acc[i][j] = __builtin_amdgcn_mfma_f32_16x16x32_bf16(bfr[j], af[i], acc[i][j], 0, 0, 0);  // swapped
    __syncthreads();
  }
  // epilogue: lane holds d = n0+wn*64+j*16+(l>>4)*4+r ; m = m0+wm*64+i*16+(l&15)
  const int lr = l & 15;
  int fl[4]; float rd[4]; bool cs[4];
  #pragma unroll
  for (int i = 0; i < 4; ++i) {
    const int m = m0 + wm*64 + i*16 + lr;
    fl[i] = rowfl[m];
    rd[i] = rdt[b*32 + fl[i]];
    const int cls = fl[i] & 3;
    cs[i] = (cls == 0 && (fl[i]&4)) || (cls == 1 && (fl[i]&8)) || (cls == 2 && (fl[i]&16));
  }
  #pragma unroll
  for (int j = 0; j < 4; ++j) {
    const int dg = n0 + wn*64 + j*16 + (l >> 4)*4;
    const f32x4 bi4 = *(const f32x4*)(bias + dg);
    #pragma unroll
    for (int i = 0; i < 4; ++i) {
      const int m = m0 + wm*64 + i*16 + lr;
      f32x4 val = *(const f32x4*)(V + ((size_t)(b*32 + fl[i]))*512 + dg);
      if (!cs[i]) val += (acc[i][j] + bi4) * rd[i];
      u16x4 o;
      #pragma unroll
      for (int r = 0; r < 4; ++r) o[r] = f2b(fmaxf(val[r], 0.f));
      *(u16x4*)(G + (size_t)m*512 + dg) = o;
    }
  }
}

// ---------- GEMM2 fused: val = V[fl] + (g1@W2^T + b2)*rdeg, LDS-transposed -> out (B,S,N) f32 ----------
__global__ __launch_bounds__(256) void k_gemm2f(const u16* __restrict__ A, const u16* __restrict__ Bw,
                       const float* __restrict__ bias, const float* __restrict__ V,
                       const float* __restrict__ rdt, const int* __restrict__ rowfl,
                       float* __restrict__ out) {
  __shared__ u16 As[128*32];
  __shared__ u16 Bs[128*32];
  __shared__ float ep[64][130];
  const int tid = threadIdx.x;
  const int w = tid >> 6, l = tid & 63;
  const int wm = w >> 1, wn = w & 1;
  const int m0 = blockIdx.x * 128, n0 = blockIdx.y * 128;
  const int b = m0 >> 11;
  f32x4 acc[4][4];
  #pragma unroll
  for (int i = 0; i < 4; ++i)
    #pragma unroll
    for (int j = 0; j < 4; ++j) acc[i][j] = (f32x4){0.f, 0.f, 0.f, 0.f};
  const int srow = l >> 2, skk = (l & 3) * 8;
  for (int kt = 0; kt < 512; kt += 32) {
    #pragma unroll
    for (int p = 0; p < 2; ++p) {
      const int q = w*2 + p;
      GLOAD16(A  + (size_t)(m0 + q*16 + srow)*512 + kt + skk, As + q*512);
      GLOAD16(Bw + (size_t)(n0 + q*16 + srow)*512 + kt + skk, Bs + q*512);
    }
    __syncthreads();
    bf16x8 af[4], bfr[4];
    const int lr = l & 15, lk = (l >> 4) * 8;
    #pragma unroll
    for (int i = 0; i < 4; ++i) af[i] = *(const bf16x8*)(As + (wm*64 + i*16 + lr)*32 + lk);
    #pragma unroll
    for (int j = 0; j < 4; ++j) bfr[j] = *(const bf16x8*)(Bs + (wn*64 + j*16 + lr)*32 + lk);
    #pragma unroll
    for (int i = 0; i < 4; ++i)
      #pragma unroll
      for (int j = 0; j < 4; ++j)
        acc[i][j] = __builtin_amdgcn_mfma_f32_16x16x32_bf16(bfr[j], af[i], acc[i][j], 0, 0, 0);  // swapped
    __syncthreads();
  }
  const int lr = l & 15;
  int fl[4]; float rd[4]; bool cs[4];
  #pragma unroll
  for (int i = 0; i < 4; ++i) {
    const int m = m0 + wm*64 + i*16 + lr;
    fl[i] = rowfl[m];
    rd[i] = rdt[b*32 + fl[i]];
    const int cls = fl[i] & 3;
    cs[i] = (cls == 0 && (fl[i]&4)) || (cls == 1 && (fl[i]&8)) || (cls == 2 && (fl[i]&16));
  }
  const int nloc = m0 & 2047;   // node base within batch
  #pragma unroll
  for (int p = 0; p < 2; ++p) {
    #pragma unroll
    for (int jj = 0; jj < 2; ++jj) {
      const int j = 2*p + jj;
      const int dg = n0 + wn*64 + j*16 + (l >> 4)*4;
      const int dc = wn*32 + jj*16 + (l >> 4)*4;
      const f32x4 bi4 = *(const f32x4*)(bias + dg);
      #pragma unroll
      for (int i = 0; i < 4; ++i) {
        const int mloc = wm*64 + i*16 + lr;
        f32x4 val = *(const f32x4*)(V + ((size_t)(b*32 + fl[i]))*512 + dg);
        if (!cs[i]) val += (acc[i][j] + bi4) * rd[i];
        #pragma unroll
        for (int r = 0; r < 4; ++r) ep[dc + r][mloc] = val[r];
      }
    }
    __syncthreads();
    // readback transposed: wave w handles 16 dc rows; 64 lanes x f32x2 = 128 n contiguous
    for (int rr = 0; rr < 16; ++rr) {
      const int dc = w*16 + rr;
      const int wnn = dc >> 5, jj2 = (dc >> 4) & 1, within = dc & 15;
      const int s = n0 + wnn*64 + (2*p + jj2)*16 + within;
      float2 v2 = *(const float2*)&ep[dc][2*l];
      *(float2*)(out + ((size_t)b*SS + s)*NN + nloc + 2*l) = v2;
    }
    __syncthreads();
  }
}

extern "C" void kernel_launch(void* const* d_in, const int* in_sizes, int n_in,
                              void* d_out, int out_size, void* d_ws, size_t ws_size,
                              hipStream_t stream) {
  const float* x  = (const float*)d_in[0];
  const float* W1 = (const float*)d_in[1];
  const float* b1 = (const float*)d_in[2];
  const float* W2 = (const float*)d_in[3];
  const float* b2 = (const float*)d_in[4];
  float* out = (float*)d_out;
  char* ws = (char*)d_ws;

  float* fvp   = (float*)(ws + 0);           // 1 MB
  int*   meta  = (int*)  (ws + 1048576);     // 1 KB
  int*   rowfl = (int*)  (ws + 1049600);     // 64 KB
  float* xs    = (float*)(ws + 1115136);     // 192 KB
  float* g1s   = (float*)(ws + 1311744);     // 192 KB
  float* V1    = (float*)(ws + 1508352);     // 512 KB
  float* V2    = (float*)(ws + 2032640);     // 512 KB
  float* rdt1  = (float*)(ws + 2556928);     // 4 KB
  float* rdt2  = (float*)(ws + 2561024);     // 4 KB
  u16*   w1b   = (u16*)  (ws + 2565120);     // 512 KB
  u16*   w2b   = (u16*)  (ws + 3089408);     // 512 KB
  float* w1t   = (float*)(ws + 3613696);     // 1 MB
  float* w2t   = (float*)(ws + 4662272);     // 1 MB
  u16*   g1    = (u16*)  (ws + 5710848);     // 16 MB
  u16*   xrb   = (u16*)  (ws + 22488064);    // 16 MB

  k_txr<<<dim3(NN/32, SS/32, BB), dim3(32, 8), 0, stream>>>(x, xrb, fvp);
  k_topk<<<BB, 256, 0, stream>>>(fvp, meta, rowfl, xs, g1s);
  k_wprep<<<dim3(16, 16, 2), dim3(32, 8), 0, stream>>>(W1, W2, w1b, w2b, w1t, w2t);
  k_rowsums<<<BB*33, 256, 0, stream>>>(xrb, meta, rowfl, xs);
  k_sgemm<<<dim3(4, BB), 512, 0, stream>>>(xs, w1t, b1, meta, V1, rdt1);
  k_gemm1f<<<dim3(MM/128, 4), 256, 0, stream>>>(xrb, w1b, b1, V1, rdt1, rowfl, g1);
  k_rowsums<<<BB*33, 256, 0, stream>>>(g1, meta, rowfl, g1s);
  k_sgemm<<<dim3(4, BB), 512, 0, stream>>>(g1s, w2t, b2, meta, V2, rdt2);
  k_gemm2f<<<dim3(MM/128, 4), 256, 0, stream>>>(g1, w2b, b2, V2, rdt2, rowfl, out);
}